// Round 7
// baseline (90.967 us; speedup 1.0000x reference)
//
#include <hip/hip_runtime.h>
#include <hip/hip_bf16.h>

// x: [4, 4096, 4096] f32, W1: [48, 4096] f32, W2: [48, 48] f32
// out: [4, 4, 4096, 12] f32  (C, B, T, L/C)
#define DDIM 4096
#define LTOT 48

typedef __attribute__((ext_vector_type(4))) float f32x4;
typedef __attribute__((ext_vector_type(8))) short bf16x8;

__device__ __forceinline__ void gload_lds16(const void* g, void* l) {
    __builtin_amdgcn_global_load_lds(
        (const __attribute__((address_space(1))) void*)g,
        (__attribute__((address_space(3))) void*)l, 16, 0, 0);
}

__device__ __forceinline__ unsigned cvt_pk(float x, float y) {
    union { __hip_bfloat162 h; unsigned u; } c;
    c.h = __float22bfloat162_rn(make_float2(x, y));
    return c.u;
}

// ---- kernel 0: W1 fp32 -> bf16 (RNE) into workspace ----
__global__ void w1cvt_kernel(const float* __restrict__ w1, ushort* __restrict__ w1b) {
    int i = blockIdx.x * 256 + threadIdx.x;
    union { float f; unsigned u; } v; v.f = w1[i];
    unsigned r = v.u + 0x7fffu + ((v.u >> 16) & 1u);
    w1b[i] = (ushort)(r >> 16);
}

// ---- fused: 16-row tile, K macro-chunks of 512 cols staged as 2KB/row
//      contiguous bursts (page-activation amortization), 4 waves K-split
//      within each staged macro, raw-barrier + counted-vmcnt pipeline ----
__global__ __launch_bounds__(256, 2) void fused_kernel(
        const float* __restrict__ x,
        const ushort* __restrict__ w1b,
        const float* __restrict__ w2,
        float* __restrict__ out) {
    // 2 x 32KB staging buffers (16 rows x 2048B); epilogue overlays after sync
    __shared__ __align__(16) char smem[65536];

    const int tid  = threadIdx.x;
    const int wave = tid >> 6;
    const int lane = tid & 63;
    const int rl   = lane & 15;   // A-row / B-row / C-col
    const int kg   = lane >> 4;   // k-group 0..3
    const int row0 = blockIdx.x * 16;

    // stage macro c: this wave stages rows 4*wave..4*wave+3, 2x1KB per row.
    // LDS dest linear; global source lane-permuted (slot low4 ^= row) so the
    // swizzled ds_read below sees the right data (both-sides swizzle, m173).
    auto stage = [&](int c) {
        char* buf = smem + (c & 1) * 32768;
        #pragma unroll
        for (int r2 = 0; r2 < 4; ++r2) {
            const int row = wave * 4 + r2;
            const float* srcb = x + (size_t)(row0 + row) * DDIM + c * 512;
            #pragma unroll
            for (int j = 0; j < 2; ++j) {
                int s = j * 64 + lane;
                int srcslot = (s & ~15) | ((s ^ row) & 15);
                gload_lds16(srcb + srcslot * 4, buf + row * 2048 + j * 1024);
            }
        }
    };

    f32x4 acc[3] = {{0.f,0.f,0.f,0.f},{0.f,0.f,0.f,0.f},{0.f,0.f,0.f,0.f}};
    float ss = 0.f;

    stage(0);   // prologue: 8 DMA in flight

    #pragma unroll
    for (int c = 0; c < 8; ++c) {
        // my ds_reads of buf (c-1) are complete (consumed); fence + phase-lock
        asm volatile("s_waitcnt lgkmcnt(0)" ::: "memory");
        __builtin_amdgcn_s_barrier();       // raw: no vmcnt drain

        // B fragments for my K-window of macro c (12 loads, BEFORE stage(c+1)
        // so the compiler's B-use wait is vmcnt(8) and keeps stage in flight)
        bf16x8 Bf[4][3];
        #pragma unroll
        for (int t = 0; t < 4; ++t)
            #pragma unroll
            for (int n = 0; n < 3; ++n)
                Bf[t][n] = *(const bf16x8*)(w1b + (size_t)(n * 16 + rl) * DDIM
                                            + c * 512 + wave * 128 + t * 32 + kg * 8);
        __builtin_amdgcn_sched_barrier(0);
        if (c < 7) stage(c + 1);            // 8 DMA into the freed buffer
        __builtin_amdgcn_sched_barrier(0);

        // stage(c) complete: newer = B(c)[12] + stage(c+1)[8]
        if (c < 7) asm volatile("s_waitcnt vmcnt(20)" ::: "memory");
        else       asm volatile("s_waitcnt vmcnt(12)" ::: "memory");

        const char* buf = smem + (c & 1) * 32768 + rl * 2048;
        #pragma unroll
        for (int t = 0; t < 4; ++t) {
            f32x4 A[2];
            #pragma unroll
            for (int p = 0; p < 2; ++p) {
                int g = wave * 32 + t * 8 + kg * 2 + p;
                int sp = (g & ~15) | ((g ^ rl) & 15);
                A[p] = *(const f32x4*)(buf + sp * 16);
            }
            f32x4 a0 = A[0], a1 = A[1];
            ss = fmaf(a0.x, a0.x, ss); ss = fmaf(a0.y, a0.y, ss);
            ss = fmaf(a0.z, a0.z, ss); ss = fmaf(a0.w, a0.w, ss);
            ss = fmaf(a1.x, a1.x, ss); ss = fmaf(a1.y, a1.y, ss);
            ss = fmaf(a1.z, a1.z, ss); ss = fmaf(a1.w, a1.w, ss);
            union { bf16x8 v; unsigned u[4]; } af;
            af.u[0] = cvt_pk(a0.x, a0.y); af.u[1] = cvt_pk(a0.z, a0.w);
            af.u[2] = cvt_pk(a1.x, a1.y); af.u[3] = cvt_pk(a1.z, a1.w);
            #pragma unroll
            for (int n = 0; n < 3; ++n)
                acc[n] = __builtin_amdgcn_mfma_f32_16x16x32_bf16(
                             af.v, Bf[t][n], acc[n], 0, 0, 0);
        }
    }

    // ---- reductions & epilogue (R2/R6-proven), LDS overlay ----
    ss += __shfl_xor(ss, 16);
    ss += __shfl_xor(ss, 32);
    __syncthreads();   // full drain once; staging LDS now reusable

    float* dots = (float*)smem;             // [4][16][48] = 12288 B
    float* ssw  = (float*)(smem + 12288);   // [4][16]
    float* scl  = (float*)(smem + 12544);   // [16]
    float* gbuf = (float*)(smem + 12608);   // [16][48]
    float* w2s  = (float*)(smem + 15680);   // [48][48]

    if (lane < 16) ssw[wave * 16 + lane] = ss;

    #pragma unroll
    for (int n = 0; n < 3; ++n)
        #pragma unroll
        for (int i = 0; i < 4; ++i)
            dots[(wave * 16 + kg * 4 + i) * 48 + n * 16 + rl] = acc[n][i];

    for (int i = tid; i < LTOT * LTOT; i += 256) w2s[i] = w2[i];
    __syncthreads();

    if (tid < 16) {
        float st = ssw[0 * 16 + tid] + ssw[1 * 16 + tid]
                 + ssw[2 * 16 + tid] + ssw[3 * 16 + tid];
        scl[tid] = rsqrtf(st * (1.0f / (float)DDIM) + 1e-5f);
    }
    __syncthreads();

    #pragma unroll
    for (int i = 0; i < 3; ++i) {
        int v = tid + i * 256;
        int row = v / 48, col = v - row * 48;
        float d = dots[(0 * 16 + row) * 48 + col] + dots[(1 * 16 + row) * 48 + col]
                + dots[(2 * 16 + row) * 48 + col] + dots[(3 * 16 + row) * 48 + col];
        float h = d * scl[row];
        gbuf[row * 48 + col] = h * 0.5f * (1.0f + erff(h * 0.70710678118654752f));
    }
    __syncthreads();

    #pragma unroll
    for (int i = 0; i < 3; ++i) {
        int v = tid + i * 256;
        int row = v / 48, l = v - row * 48;
        float sacc = 0.f;
        #pragma unroll
        for (int k = 0; k < LTOT; ++k)
            sacc = fmaf(gbuf[row * 48 + k], w2s[l * LTOT + k], sacc);
        int rg = row0 + row;
        int b  = rg >> 12;
        int t  = rg & 4095;
        int cc = l / 12, j = l - cc * 12;
        out[(((size_t)(cc * 4 + b) * 4096 + t) * 12) + j] = sacc;
    }
}

extern "C" void kernel_launch(void* const* d_in, const int* in_sizes, int n_in,
                              void* d_out, int out_size, void* d_ws, size_t ws_size,
                              hipStream_t stream) {
    const float* x  = (const float*)d_in[0];
    const float* W1 = (const float*)d_in[1];
    const float* W2 = (const float*)d_in[2];
    float* out = (float*)d_out;
    ushort* w1b = (ushort*)d_ws;

    w1cvt_kernel<<<(LTOT * DDIM) / 256, 256, 0, stream>>>(W1, w1b);
    fused_kernel<<<16384 / 16, 256, 0, stream>>>(x, w1b, W2, out);
}

// Round 8
// 77.722 us; speedup vs baseline: 1.1704x; 1.1704x over previous
//
#include <hip/hip_runtime.h>
#include <hip/hip_bf16.h>

// x: [4, 4096, 4096] f32, W1: [48, 4096] f32, W2: [48, 48] f32
// out: [4, 4, 4096, 12] f32  (C, B, T, L/C)
#define DDIM 4096
#define LTOT 48

typedef __attribute__((ext_vector_type(4))) float f32x4;
typedef __attribute__((ext_vector_type(8))) short bf16x8;

// NT (non-temporal, CPol bit 1) on the streaming x loads: x is read exactly
// once, so demote it to evict-first and keep W1b resident in L2.
__device__ __forceinline__ void gload_lds16_nt(const void* g, void* l) {
    __builtin_amdgcn_global_load_lds(
        (const __attribute__((address_space(1))) void*)g,
        (__attribute__((address_space(3))) void*)l, 16, 0, /*aux=NT*/2);
}

__device__ __forceinline__ unsigned cvt_pk(float x, float y) {
    union { __hip_bfloat162 h; unsigned u; } c;
    c.h = __float22bfloat162_rn(make_float2(x, y));
    return c.u;
}

// ---- kernel 0: W1 fp32 -> bf16 (RNE) into workspace ----
__global__ void w1cvt_kernel(const float* __restrict__ w1, ushort* __restrict__ w1b) {
    int i = blockIdx.x * 256 + threadIdx.x;
    union { float f; unsigned u; } v; v.f = w1[i];
    unsigned r = v.u + 0x7fffu + ((v.u >> 16) & 1u);
    w1b[i] = (ushort)(r >> 16);
}

// ---- fused: async-staged sumsq + x@W1^T + rms + gelu + @W2^T + store ----
// (byte-identical to the round-2 kernel except NT on the x DMA loads)
__global__ __launch_bounds__(256, 4) void fused_kernel(
        const float* __restrict__ x,
        const ushort* __restrict__ w1b,
        const float* __restrict__ w2,
        float* __restrict__ out) {
    // staging: 4 waves x 2 buffers x 4096B (16 rows x 64 f32, XOR-swizzled 16B blocks)
    __shared__ __align__(1024) char smem[32768];
    __shared__ float ssw[4][16];
    __shared__ float scl[16];

    const int tid  = threadIdx.x;
    const int wave = tid >> 6;
    const int lane = tid & 63;
    const int rl   = lane & 15;   // A-row / B-row / C-col
    const int kg   = lane >> 4;   // k-group 0..3
    const int row0 = blockIdx.x * 16;
    const int kw   = wave * 1024; // per-wave K range

    char* wbase = smem + wave * 8192;

    // ds_read byte offsets within one buffer for (half h, piece p):
    // global 16B-block g = h*8 + kg*2 + p lives at LDS block g ^ rl of row rl
    int dso[2][2];
    #pragma unroll
    for (int h = 0; h < 2; ++h)
        #pragma unroll
        for (int p = 0; p < 2; ++p)
            dso[h][p] = rl * 256 + (((h * 8 + kg * 2 + p) ^ rl) << 4);

    // stage K-step t into buffer t&1 (4 x 1KB global_load_lds, linear dest,
    // inverse-swizzled per-lane global source)
    auto stage = [&](int t) {
        const int kb = kw + t * 64;
        char* lb = wbase + (t & 1) * 4096;
        #pragma unroll
        for (int i = 0; i < 4; ++i) {
            int rloc = i * 4 + kg;           // row this lane's 16B lands in
            int blkg = rl ^ rloc;            // source block (inverse swizzle)
            const float* src = x + (size_t)(row0 + rloc) * DDIM + kb + blkg * 4;
            gload_lds16_nt(src, lb + i * 1024);
        }
    };

    // B fragments for K-step s (6 x 16B, L2-resident)
    auto loadB = [&](int s, bf16x8 (&bl)[6]) {
        const ushort* bp = w1b + (size_t)rl * DDIM + kw + s * 64 + kg * 8;
        #pragma unroll
        for (int n = 0; n < 3; ++n)
            #pragma unroll
            for (int h = 0; h < 2; ++h)
                bl[n * 2 + h] = *(const bf16x8*)(bp + n * 16 * DDIM + h * 32);
    };

    float ss = 0.f;
    f32x4 acc[3] = {{0.f,0.f,0.f,0.f},{0.f,0.f,0.f,0.f},{0.f,0.f,0.f,0.f}};
    bf16x8 bA[6], bB[6];

    // prologue: two buffers in flight + first B
    stage(0); stage(1); loadB(0, bA);

    auto body = [&](int s, bf16x8 (&bu)[6], bf16x8 (&bl)[6]) {
        // stage(s) done when <=4 vmem outstanding (stage(s+1) stays in flight)
        asm volatile("s_waitcnt vmcnt(4)" ::: "memory");
        char* lb = wbase + (s & 1) * 4096;
        f32x4 a[2][2];
        #pragma unroll
        for (int h = 0; h < 2; ++h)
            #pragma unroll
            for (int p = 0; p < 2; ++p)
                a[h][p] = *(const f32x4*)(lb + dso[h][p]);
        if (s < 15) loadB(s + 1, bl);   // B one step ahead (reg double-buffer)
        #pragma unroll
        for (int h = 0; h < 2; ++h) {
            f32x4 a0 = a[h][0], a1 = a[h][1];
            ss = fmaf(a0.x, a0.x, ss); ss = fmaf(a0.y, a0.y, ss);
            ss = fmaf(a0.z, a0.z, ss); ss = fmaf(a0.w, a0.w, ss);
            ss = fmaf(a1.x, a1.x, ss); ss = fmaf(a1.y, a1.y, ss);
            ss = fmaf(a1.z, a1.z, ss); ss = fmaf(a1.w, a1.w, ss);
            union { bf16x8 v; unsigned u[4]; } af;
            af.u[0] = cvt_pk(a0.x, a0.y); af.u[1] = cvt_pk(a0.z, a0.w);
            af.u[2] = cvt_pk(a1.x, a1.y); af.u[3] = cvt_pk(a1.z, a1.w);
            #pragma unroll
            for (int n = 0; n < 3; ++n)
                acc[n] = __builtin_amdgcn_mfma_f32_16x16x32_bf16(
                             af.v, bu[n * 2 + h], acc[n], 0, 0, 0);
        }
        // ds_reads of this buffer must land before we overwrite it
        asm volatile("s_waitcnt lgkmcnt(0)" ::: "memory");
        if (s < 14) stage(s + 2);
    };

    for (int sp = 0; sp < 8; ++sp) {
        body(2 * sp,     bA, bB);
        body(2 * sp + 1, bB, bA);
    }

    // ---- reductions ----
    ss += __shfl_xor(ss, 16);
    ss += __shfl_xor(ss, 32);
    if (lane < 16) ssw[wave][lane] = ss;
    __syncthreads();   // all waves done with staging LDS -> safe to overlay

    float* dots = (float*)smem;            // [4][16][48] f32 = 12288 B
    float* gbuf = (float*)(smem + 12288);  // [16][48]    f32 =  3072 B
    float* w2s  = (float*)(smem + 15360);  // [48*48]     f32 =  9216 B

    #pragma unroll
    for (int n = 0; n < 3; ++n)
        #pragma unroll
        for (int i = 0; i < 4; ++i)
            dots[(wave * 16 + kg * 4 + i) * 48 + n * 16 + rl] = acc[n][i];
    for (int i = tid; i < LTOT * LTOT; i += 256) w2s[i] = w2[i];
    __syncthreads();

    if (tid < 16) {
        float st = ssw[0][tid] + ssw[1][tid] + ssw[2][tid] + ssw[3][tid];
        scl[tid] = rsqrtf(st * (1.0f / (float)DDIM) + 1e-5f);
    }
    __syncthreads();

    #pragma unroll
    for (int i = 0; i < 3; ++i) {
        int v = tid + i * 256;
        int row = v / 48, col = v - row * 48;
        float d = dots[(0 * 16 + row) * 48 + col] + dots[(1 * 16 + row) * 48 + col]
                + dots[(2 * 16 + row) * 48 + col] + dots[(3 * 16 + row) * 48 + col];
        float h = d * scl[row];
        gbuf[row * 48 + col] = h * 0.5f * (1.0f + erff(h * 0.70710678118654752f));
    }
    __syncthreads();

    #pragma unroll
    for (int i = 0; i < 3; ++i) {
        int v = tid + i * 256;
        int row = v / 48, l = v - row * 48;
        float sacc = 0.f;
        #pragma unroll
        for (int k = 0; k < LTOT; ++k)
            sacc = fmaf(gbuf[row * 48 + k], w2s[l * LTOT + k], sacc);
        int rg = row0 + row;
        int b  = rg >> 12;
        int t  = rg & 4095;
        int c  = l / 12, j = l - c * 12;
        out[(((size_t)(c * 4 + b) * 4096 + t) * 12) + j] = sacc;
    }
}

extern "C" void kernel_launch(void* const* d_in, const int* in_sizes, int n_in,
                              void* d_out, int out_size, void* d_ws, size_t ws_size,
                              hipStream_t stream) {
    const float* x  = (const float*)d_in[0];
    const float* W1 = (const float*)d_in[1];
    const float* W2 = (const float*)d_in[2];
    float* out = (float*)d_out;
    ushort* w1b = (ushort*)d_ws;

    w1cvt_kernel<<<(LTOT * DDIM) / 256, 256, 0, stream>>>(W1, w1b);
    fused_kernel<<<16384 / 16, 256, 0, stream>>>(x, w1b, W2, out);
}

// Round 9
// 69.908 us; speedup vs baseline: 1.3012x; 1.1118x over previous
//
#include <hip/hip_runtime.h>
#include <hip/hip_bf16.h>

// x: [4, 4096, 4096] f32, W1: [48, 4096] f32, W2: [48, 48] f32
// out: [4, 4, 4096, 12] f32  (C, B, T, L/C)
#define DDIM 4096
#define LTOT 48

typedef __attribute__((ext_vector_type(4))) float f32x4;
typedef __attribute__((ext_vector_type(8))) short bf16x8;

__device__ __forceinline__ void gload_lds16(const void* g, void* l) {
    __builtin_amdgcn_global_load_lds(
        (const __attribute__((address_space(1))) void*)g,
        (__attribute__((address_space(3))) void*)l, 16, 0, 0);
}

__device__ __forceinline__ unsigned cvt_pk(float x, float y) {
    union { __hip_bfloat162 h; unsigned u; } c;
    c.h = __float22bfloat162_rn(make_float2(x, y));
    return c.u;
}

// ---- kernel 0: W1 fp32 -> bf16 (RNE) into workspace ----
__global__ void w1cvt_kernel(const float* __restrict__ w1, ushort* __restrict__ w1b) {
    int i = blockIdx.x * 256 + threadIdx.x;
    union { float f; unsigned u; } v; v.f = w1[i];
    unsigned r = v.u + 0x7fffu + ((v.u >> 16) & 1u);
    w1b[i] = (ushort)(r >> 16);
}

// ---- fused kernel: exact round-2 structure + per-block K-phase rotation ----
// Rotation decorrelates the chip-wide column sweep so concurrent requests
// cover all DRAM channels instead of one synchronized 256B window.
__global__ __launch_bounds__(256, 4) void fused_kernel(
        const float* __restrict__ x,
        const ushort* __restrict__ w1b,
        const float* __restrict__ w2,
        float* __restrict__ out) {
    // staging: 4 waves x 2 buffers x 4096B (16 rows x 64 f32, XOR-swizzled 16B blocks)
    __shared__ __align__(1024) char smem[32768];
    __shared__ float ssw[4][16];
    __shared__ float scl[16];

    const int tid  = threadIdx.x;
    const int wave = tid >> 6;
    const int lane = tid & 63;
    const int rl   = lane & 15;   // A-row / B-row / C-col
    const int kg   = lane >> 4;   // k-group 0..3
    const int row0 = blockIdx.x * 16;
    const int kw   = wave * 1024; // per-wave K range
    const int rot  = blockIdx.x & 15;   // per-block K-phase rotation

    char* wbase = smem + wave * 8192;

    // ds_read byte offsets within one buffer for (half h, piece p):
    // global 16B-block g = h*8 + kg*2 + p lives at LDS block g ^ rl of row rl
    int dso[2][2];
    #pragma unroll
    for (int h = 0; h < 2; ++h)
        #pragma unroll
        for (int p = 0; p < 2; ++p)
            dso[h][p] = rl * 256 + (((h * 8 + kg * 2 + p) ^ rl) << 4);

    // stage pipeline-step t into buffer t&1; K-chunk = (t + rot) & 15
    auto stage = [&](int t) {
        const int kb = kw + ((t + rot) & 15) * 64;
        char* lb = wbase + (t & 1) * 4096;
        #pragma unroll
        for (int i = 0; i < 4; ++i) {
            int rloc = i * 4 + kg;           // row this lane's 16B lands in
            int blkg = rl ^ rloc;            // source block (inverse swizzle)
            const float* src = x + (size_t)(row0 + rloc) * DDIM + kb + blkg * 4;
            gload_lds16(src, lb + i * 1024);
        }
    };

    // B fragments for pipeline-step s (6 x 16B, L2-resident): same rotation
    auto loadB = [&](int s, bf16x8 (&bl)[6]) {
        const ushort* bp = w1b + (size_t)rl * DDIM + kw + ((s + rot) & 15) * 64 + kg * 8;
        #pragma unroll
        for (int n = 0; n < 3; ++n)
            #pragma unroll
            for (int h = 0; h < 2; ++h)
                bl[n * 2 + h] = *(const bf16x8*)(bp + n * 16 * DDIM + h * 32);
    };

    float ss = 0.f;
    f32x4 acc[3] = {{0.f,0.f,0.f,0.f},{0.f,0.f,0.f,0.f},{0.f,0.f,0.f,0.f}};
    bf16x8 bA[6], bB[6];

    // prologue: two buffers in flight + first B
    stage(0); stage(1); loadB(0, bA);

    auto body = [&](int s, bf16x8 (&bu)[6], bf16x8 (&bl)[6]) {
        // stage(s) done when <=4 vmem outstanding (stage(s+1) stays in flight)
        asm volatile("s_waitcnt vmcnt(4)" ::: "memory");
        char* lb = wbase + (s & 1) * 4096;
        f32x4 a[2][2];
        #pragma unroll
        for (int h = 0; h < 2; ++h)
            #pragma unroll
            for (int p = 0; p < 2; ++p)
                a[h][p] = *(const f32x4*)(lb + dso[h][p]);
        if (s < 15) loadB(s + 1, bl);   // B one step ahead (reg double-buffer)
        #pragma unroll
        for (int h = 0; h < 2; ++h) {
            f32x4 a0 = a[h][0], a1 = a[h][1];
            ss = fmaf(a0.x, a0.x, ss); ss = fmaf(a0.y, a0.y, ss);
            ss = fmaf(a0.z, a0.z, ss); ss = fmaf(a0.w, a0.w, ss);
            ss = fmaf(a1.x, a1.x, ss); ss = fmaf(a1.y, a1.y, ss);
            ss = fmaf(a1.z, a1.z, ss); ss = fmaf(a1.w, a1.w, ss);
            union { bf16x8 v; unsigned u[4]; } af;
            af.u[0] = cvt_pk(a0.x, a0.y); af.u[1] = cvt_pk(a0.z, a0.w);
            af.u[2] = cvt_pk(a1.x, a1.y); af.u[3] = cvt_pk(a1.z, a1.w);
            #pragma unroll
            for (int n = 0; n < 3; ++n)
                acc[n] = __builtin_amdgcn_mfma_f32_16x16x32_bf16(
                             af.v, bu[n * 2 + h], acc[n], 0, 0, 0);
        }
        // ds_reads of this buffer must land before we overwrite it
        asm volatile("s_waitcnt lgkmcnt(0)" ::: "memory");
        if (s < 14) stage(s + 2);
    };

    for (int sp = 0; sp < 8; ++sp) {
        body(2 * sp,     bA, bB);
        body(2 * sp + 1, bB, bA);
    }

    // ---- reductions ----
    ss += __shfl_xor(ss, 16);
    ss += __shfl_xor(ss, 32);
    if (lane < 16) ssw[wave][lane] = ss;
    __syncthreads();   // all waves done with staging LDS -> safe to overlay

    float* dots = (float*)smem;            // [4][16][48] f32 = 12288 B
    float* gbuf = (float*)(smem + 12288);  // [16][48]    f32 =  3072 B
    float* w2s  = (float*)(smem + 15360);  // [48*48]     f32 =  9216 B

    #pragma unroll
    for (int n = 0; n < 3; ++n)
        #pragma unroll
        for (int i = 0; i < 4; ++i)
            dots[(wave * 16 + kg * 4 + i) * 48 + n * 16 + rl] = acc[n][i];
    for (int i = tid; i < LTOT * LTOT; i += 256) w2s[i] = w2[i];
    __syncthreads();

    if (tid < 16) {
        float st = ssw[0][tid] + ssw[1][tid] + ssw[2][tid] + ssw[3][tid];
        scl[tid] = rsqrtf(st * (1.0f / (float)DDIM) + 1e-5f);
    }
    __syncthreads();

    #pragma unroll
    for (int i = 0; i < 3; ++i) {
        int v = tid + i * 256;
        int row = v / 48, col = v - row * 48;
        float d = dots[(0 * 16 + row) * 48 + col] + dots[(1 * 16 + row) * 48 + col]
                + dots[(2 * 16 + row) * 48 + col] + dots[(3 * 16 + row) * 48 + col];
        float h = d * scl[row];
        gbuf[row * 48 + col] = h * 0.5f * (1.0f + erff(h * 0.70710678118654752f));
    }
    __syncthreads();

    #pragma unroll
    for (int i = 0; i < 3; ++i) {
        int v = tid + i * 256;
        int row = v / 48, l = v - row * 48;
        float sacc = 0.f;
        #pragma unroll
        for (int k = 0; k < LTOT; ++k)
            sacc = fmaf(gbuf[row * 48 + k], w2s[l * LTOT + k], sacc);
        int rg = row0 + row;
        int b  = rg >> 12;
        int t  = rg & 4095;
        int c  = l / 12, j = l - c * 12;
        out[(((size_t)(c * 4 + b) * 4096 + t) * 12) + j] = sacc;
    }
}

extern "C" void kernel_launch(void* const* d_in, const int* in_sizes, int n_in,
                              void* d_out, int out_size, void* d_ws, size_t ws_size,
                              hipStream_t stream) {
    const float* x  = (const float*)d_in[0];
    const float* W1 = (const float*)d_in[1];
    const float* W2 = (const float*)d_in[2];
    float* out = (float*)d_out;
    ushort* w1b = (ushort*)d_ws;

    w1cvt_kernel<<<(LTOT * DDIM) / 256, 256, 0, stream>>>(W1, w1b);
    fused_kernel<<<16384 / 16, 256, 0, stream>>>(x, w1b, W2, out);
}

// Round 10
// 58.517 us; speedup vs baseline: 1.5545x; 1.1946x over previous
//
#include <hip/hip_runtime.h>
#include <hip/hip_bf16.h>

// x: [4, 4096, 4096] f32, W1: [48, 4096] f32, W2: [48, 48] f32
// out: [4, 4, 4096, 12] f32  (C, B, T, L/C)
#define DDIM 4096
#define LTOT 48

typedef __attribute__((ext_vector_type(4))) float f32x4;
typedef __attribute__((ext_vector_type(8))) short bf16x8;

__device__ __forceinline__ void gload_lds16(const void* g, void* l) {
    __builtin_amdgcn_global_load_lds(
        (const __attribute__((address_space(1))) void*)g,
        (__attribute__((address_space(3))) void*)l, 16, 0, 0);
}

__device__ __forceinline__ unsigned cvt_pk(float x, float y) {
    union { __hip_bfloat162 h; unsigned u; } c;
    c.h = __float22bfloat162_rn(make_float2(x, y));
    return c.u;
}

// ---- kernel 0: W1 fp32 -> bf16 (RNE) into workspace ----
__global__ void w1cvt_kernel(const float* __restrict__ w1, ushort* __restrict__ w1b) {
    int i = blockIdx.x * 256 + threadIdx.x;
    union { float f; unsigned u; } v; v.f = w1[i];
    unsigned r = v.u + 0x7fffu + ((v.u >> 16) & 1u);
    w1b[i] = (ushort)(r >> 16);
}

// ---- fused: 32-row blocks (2 MFMA row-tiles/wave), 4-wave K-split,
//      DMA-staged double buffer; halves block count and W1b L2 traffic ----
__global__ __launch_bounds__(256, 2) void fused_kernel(
        const float* __restrict__ x,
        const ushort* __restrict__ w1b,
        const float* __restrict__ w2,
        float* __restrict__ out) {
    // staging: 4 waves x 2 buffers x 8192B (32 rows x 64 f32, XOR-swizzled)
    __shared__ __align__(1024) char smem[65536];
    __shared__ float ssw[4][32];
    __shared__ float scl[32];

    const int tid  = threadIdx.x;
    const int wave = tid >> 6;
    const int lane = tid & 63;
    const int rl   = lane & 15;   // A-row (within tile) / B-row / C-col
    const int kg   = lane >> 4;   // k-group 0..3
    const int row0 = blockIdx.x * 32;
    const int kw   = wave * 1024; // per-wave K range
    const int rot  = blockIdx.x & 15;

    char* wbase = smem + wave * 16384;

    // ds_read offsets for (tile T, half h, piece p): row r = T*16+rl,
    // logical 16B-block g = h*8+kg*2+p stored at LDS pos g ^ rl of row r
    int dso[2][2][2];
    #pragma unroll
    for (int T = 0; T < 2; ++T)
        #pragma unroll
        for (int h = 0; h < 2; ++h)
            #pragma unroll
            for (int p = 0; p < 2; ++p)
                dso[T][h][p] = (T * 16 + rl) * 256 + (((h * 8 + kg * 2 + p) ^ rl) << 4);

    // stage pipeline-step t into buffer t&1: 8 x 1KB DMA (rows i*4+kg),
    // linear LDS dest, inverse-swizzled per-lane global source
    auto stage = [&](int t) {
        const int kb = kw + ((t + rot) & 15) * 64;
        char* lb = wbase + (t & 1) * 8192;
        #pragma unroll
        for (int i = 0; i < 8; ++i) {
            int r    = i * 4 + kg;           // row this lane's 16B lands in
            int blkg = rl ^ (r & 15);        // source block (inverse swizzle)
            const float* src = x + (size_t)(row0 + r) * DDIM + kb + blkg * 4;
            gload_lds16(src, lb + i * 1024);
        }
    };

    // B fragments for pipeline-step s (6 x 16B, L2-resident)
    auto loadB = [&](int s, bf16x8 (&bl)[6]) {
        const ushort* bp = w1b + (size_t)rl * DDIM + kw + ((s + rot) & 15) * 64 + kg * 8;
        #pragma unroll
        for (int n = 0; n < 3; ++n)
            #pragma unroll
            for (int h = 0; h < 2; ++h)
                bl[n * 2 + h] = *(const bf16x8*)(bp + n * 16 * DDIM + h * 32);
    };

    float ss0 = 0.f, ss1 = 0.f;
    f32x4 acc0[3] = {{0.f,0.f,0.f,0.f},{0.f,0.f,0.f,0.f},{0.f,0.f,0.f,0.f}};
    f32x4 acc1[3] = {{0.f,0.f,0.f,0.f},{0.f,0.f,0.f,0.f},{0.f,0.f,0.f,0.f}};
    bf16x8 bA[6], bB[6];

    // prologue: B0 issued BETWEEN the two stages so no wait ever drains stage(1)
    stage(0); loadB(0, bA); stage(1);

    auto body = [&](int s, bf16x8 (&bu)[6], bf16x8 (&bl)[6]) {
        // retire exactly stage(s): queue is [st(s):8][B(s):6][st(s+1):8]
        if (s == 0)       asm volatile("s_waitcnt vmcnt(14)" ::: "memory");
        else if (s == 15) asm volatile("s_waitcnt vmcnt(6)"  ::: "memory"); // [st15:8][B15:6]
        else              asm volatile("s_waitcnt vmcnt(8)"  ::: "memory");
        char* lb = wbase + (s & 1) * 8192;
        f32x4 a[2][2][2];
        #pragma unroll
        for (int T = 0; T < 2; ++T)
            #pragma unroll
            for (int h = 0; h < 2; ++h)
                #pragma unroll
                for (int p = 0; p < 2; ++p)
                    a[T][h][p] = *(const f32x4*)(lb + dso[T][h][p]);
        if (s < 15) loadB(s + 1, bl);   // B one step ahead (reg double-buffer)
        #pragma unroll
        for (int h = 0; h < 2; ++h) {
            f32x4 a0 = a[0][h][0], a1 = a[0][h][1];
            f32x4 c0 = a[1][h][0], c1 = a[1][h][1];
            ss0 = fmaf(a0.x, a0.x, ss0); ss0 = fmaf(a0.y, a0.y, ss0);
            ss0 = fmaf(a0.z, a0.z, ss0); ss0 = fmaf(a0.w, a0.w, ss0);
            ss0 = fmaf(a1.x, a1.x, ss0); ss0 = fmaf(a1.y, a1.y, ss0);
            ss0 = fmaf(a1.z, a1.z, ss0); ss0 = fmaf(a1.w, a1.w, ss0);
            ss1 = fmaf(c0.x, c0.x, ss1); ss1 = fmaf(c0.y, c0.y, ss1);
            ss1 = fmaf(c0.z, c0.z, ss1); ss1 = fmaf(c0.w, c0.w, ss1);
            ss1 = fmaf(c1.x, c1.x, ss1); ss1 = fmaf(c1.y, c1.y, ss1);
            ss1 = fmaf(c1.z, c1.z, ss1); ss1 = fmaf(c1.w, c1.w, ss1);
            union { bf16x8 v; unsigned u[4]; } af, ag;
            af.u[0] = cvt_pk(a0.x, a0.y); af.u[1] = cvt_pk(a0.z, a0.w);
            af.u[2] = cvt_pk(a1.x, a1.y); af.u[3] = cvt_pk(a1.z, a1.w);
            ag.u[0] = cvt_pk(c0.x, c0.y); ag.u[1] = cvt_pk(c0.z, c0.w);
            ag.u[2] = cvt_pk(c1.x, c1.y); ag.u[3] = cvt_pk(c1.z, c1.w);
            #pragma unroll
            for (int n = 0; n < 3; ++n) {
                acc0[n] = __builtin_amdgcn_mfma_f32_16x16x32_bf16(
                              af.v, bu[n * 2 + h], acc0[n], 0, 0, 0);
                acc1[n] = __builtin_amdgcn_mfma_f32_16x16x32_bf16(
                              ag.v, bu[n * 2 + h], acc1[n], 0, 0, 0);
            }
        }
        // ds_reads of this buffer must land before we overwrite it
        asm volatile("s_waitcnt lgkmcnt(0)" ::: "memory");
        if (s < 14) stage(s + 2);
    };

    for (int sp = 0; sp < 8; ++sp) {
        body(2 * sp,     bA, bB);
        body(2 * sp + 1, bB, bA);
    }

    // ---- reductions ----
    ss0 += __shfl_xor(ss0, 16); ss0 += __shfl_xor(ss0, 32);
    ss1 += __shfl_xor(ss1, 16); ss1 += __shfl_xor(ss1, 32);
    if (lane < 16) { ssw[wave][lane] = ss0; ssw[wave][16 + lane] = ss1; }

    asm volatile("s_waitcnt vmcnt(0) lgkmcnt(0)" ::: "memory");
    __syncthreads();   // staging LDS free -> overlay epilogue arrays

    float* dots = (float*)smem;             // [4][32][48] = 24576 B
    float* gbuf = (float*)(smem + 24576);   // [32][48]    =  6144 B
    float* w2s  = (float*)(smem + 30720);   // [48][48]    =  9216 B

    #pragma unroll
    for (int n = 0; n < 3; ++n)
        #pragma unroll
        for (int i = 0; i < 4; ++i) {
            dots[(wave * 32 + kg * 4 + i) * 48 + n * 16 + rl]      = acc0[n][i];
            dots[(wave * 32 + 16 + kg * 4 + i) * 48 + n * 16 + rl] = acc1[n][i];
        }
    for (int i = tid; i < LTOT * LTOT; i += 256) w2s[i] = w2[i];
    if (tid < 32) {
        float st = ssw[0][tid] + ssw[1][tid] + ssw[2][tid] + ssw[3][tid];
        scl[tid] = rsqrtf(st * (1.0f / (float)DDIM) + 1e-5f);
    }
    __syncthreads();

    #pragma unroll
    for (int i = 0; i < 6; ++i) {
        int v = tid + i * 256;                 // 0..1535 = 32*48
        int row = v / 48, col = v - row * 48;
        float d = dots[(0 * 32 + row) * 48 + col] + dots[(1 * 32 + row) * 48 + col]
                + dots[(2 * 32 + row) * 48 + col] + dots[(3 * 32 + row) * 48 + col];
        float h = d * scl[row];
        gbuf[row * 48 + col] = h * 0.5f * (1.0f + erff(h * 0.70710678118654752f));
    }
    __syncthreads();

    #pragma unroll
    for (int i = 0; i < 6; ++i) {
        int v = tid + i * 256;
        int row = v / 48, l = v - row * 48;
        float sacc = 0.f;
        #pragma unroll
        for (int k = 0; k < LTOT; ++k)
            sacc = fmaf(gbuf[row * 48 + k], w2s[l * LTOT + k], sacc);
        int rg = row0 + row;
        int b  = rg >> 12;
        int t  = rg & 4095;
        int c  = l / 12, j = l - c * 12;
        out[(((size_t)(c * 4 + b) * 4096 + t) * 12) + j] = sacc;
    }
}

extern "C" void kernel_launch(void* const* d_in, const int* in_sizes, int n_in,
                              void* d_out, int out_size, void* d_ws, size_t ws_size,
                              hipStream_t stream) {
    const float* x  = (const float*)d_in[0];
    const float* W1 = (const float*)d_in[1];
    const float* W2 = (const float*)d_in[2];
    float* out = (float*)d_out;
    ushort* w1b = (ushort*)d_ws;

    w1cvt_kernel<<<(LTOT * DDIM) / 256, 256, 0, stream>>>(W1, w1b);
    fused_kernel<<<16384 / 32, 256, 0, stream>>>(x, w1b, W2, out);
}